// Round 9
// baseline (71.963 us; speedup 1.0000x reference)
//
#include <hip/hip_runtime.h>
#include <hip/hip_bf16.h>

// loss = mean((output-target)^2) + ALPHA * sum(masked cosine Gram of
// V[128][196608]), V[f][d] = conv_w[o][i][f][k], d=(site,k), site=(o,i).
//
// Round 9: wave-parallel barrier-free Gram. Evidence from r8: throughput
// scales with resident waves (~0.65 TB/s per wave), not per-wave ILP. So:
// acc shrunk to 32 rows/wave (64 AGPR), 1024 gram blocks x 4 waves; every
// wave loads the full slab fragments (B) + 2 dedicated A-fragment loads at
// wave-offset ADDRESSES (register indices stay static - rule #20). Lazy
// frag build keeps peak regs low -> 8-12 waves/CU. MSE runs as co-scheduled
// blocks (ids >= 1024) of the same kernel to latency-fill. No barriers, no
// LDS staging in the gram path. pp/reduce/finalize = round-7 validated
// layouts with 1024 tiles.

typedef __attribute__((ext_vector_type(8))) short bf16x8;   // 8 bf16 = 4 VGPR
typedef __attribute__((ext_vector_type(4))) float f32x4;

#define ALPHA 0.0005f
#define TAU 0.2f

#define FDIM 128
#define NGRAM 1024          // gram blocks; 64 sites (8 octets) each
#define NMSE 2048           // mse blocks
#define NPAIRQ 8192         // packed u32 per partial tile
#define GRAM_ELEMS 16384
#define MSE_N4 2048000      // 8192*1000/4

// branchless RNE f32->bf16 pair pack
__device__ __forceinline__ unsigned int pack_bf2(float lo, float hi) {
    union { float f; unsigned int u; } a, b;
    a.f = lo; b.f = hi;
    unsigned int al = (a.u + 0x7fffu + ((a.u >> 16) & 1u)) >> 16;
    unsigned int bh = (b.u + 0x7fffu + ((b.u >> 16) & 1u)) & 0xffff0000u;
    return (al & 0xffffu) | bh;
}

// fragment: [a.x a.y a.z b.x b.y b.z 0 0] -> K-slots g*8+0..7 (6 used).
// zero pads are exact no-ops for Gram and norms. (validated round 8)
__device__ __forceinline__ bf16x8 make_frag(const float3& a, const float3& b) {
    union { bf16x8 v; unsigned int u[4]; } r;
    r.u[0] = pack_bf2(a.x, a.y);
    r.u[1] = pack_bf2(a.z, b.x);
    r.u[2] = pack_bf2(b.y, b.z);
    r.u[3] = 0;
    return r.v;
}

// One octet buffer: B-frag data for all 8 row-tiles + this wave's 2 A-tiles.
// 20 float3 = 60 VGPR while in flight.
struct OctB { float3 B[8][2]; float3 A[2][2]; };

__device__ __forceinline__ void load_oct(const float* __restrict__ lp,
                                         const float* __restrict__ lpA,
                                         OctB& o) {
#pragma unroll
    for (int tt = 0; tt < 8; ++tt) {
        o.B[tt][0] = *reinterpret_cast<const float3*>(lp + tt * 48);
        o.B[tt][1] = *reinterpret_cast<const float3*>(lp + tt * 48 + 384);
    }
#pragma unroll
    for (int a = 0; a < 2; ++a) {
        o.A[a][0] = *reinterpret_cast<const float3*>(lpA + a * 48);
        o.A[a][1] = *reinterpret_cast<const float3*>(lpA + a * 48 + 384);
    }
    __builtin_amdgcn_sched_barrier(0);      // pin loads at issue point
}

// Consume: build frags lazily (buffer regs die progressively), 16 MFMA.
__device__ __forceinline__ void consume_oct(const OctB& o,
                                            f32x4 (&acc0)[8], f32x4 (&acc1)[8]) {
    const bf16x8 fA0 = make_frag(o.A[0][0], o.A[0][1]);
    const bf16x8 fA1 = make_frag(o.A[1][0], o.A[1][1]);
#pragma unroll
    for (int cc = 0; cc < 8; ++cc) {
        const bf16x8 fb = make_frag(o.B[cc][0], o.B[cc][1]);
        acc0[cc] = __builtin_amdgcn_mfma_f32_16x16x32_bf16(fA0, fb, acc0[cc], 0, 0, 0);
        acc1[cc] = __builtin_amdgcn_mfma_f32_16x16x32_bf16(fA1, fb, acc1[cc], 0, 0, 0);
    }
}

// --------------------------------------------- mixed-role fused kernel
// blocks [0, NGRAM): Gram tile partials. blocks [NGRAM, NGRAM+NMSE): MSE.
__global__ void __launch_bounds__(256, 2) fused_kernel(
        const float* __restrict__ o, const float* __restrict__ t,
        const float* __restrict__ conv,
        float* __restrict__ mse_part, unsigned int* __restrict__ pp) {
    __shared__ float red[4];
    const int tid = threadIdx.x;
    const int lane = tid & 63;
    const int wave = tid >> 6;

    if (blockIdx.x >= NGRAM) {
        // ---------------- MSE role ----------------
        const int mb = blockIdx.x - NGRAM;
        const int gid = mb * 256 + tid;
        const f32x4* o4 = reinterpret_cast<const f32x4*>(o);
        const f32x4* t4 = reinterpret_cast<const f32x4*>(t);
        float s = 0.f;
#pragma unroll 4
        for (int i = gid; i < MSE_N4; i += NMSE * 256) {
            f32x4 a = o4[i], b = t4[i];
            f32x4 d = a - b;
            s += d[0]*d[0] + d[1]*d[1] + d[2]*d[2] + d[3]*d[3];
        }
        for (int off = 32; off; off >>= 1) s += __shfl_down(s, off);
        if (lane == 0) red[wave] = s;
        __syncthreads();
        if (tid == 0) mse_part[mb] = red[0] + red[1] + red[2] + red[3];
        return;
    }

    // ---------------- Gram role ----------------
    // block covers sites [64*blk, 64*blk+64) = 8 octets; ALL 4 waves process
    // all 8 octets, each computing its own 32-row slice (rows 32w..32w+31).
    const int g = lane >> 4;                // lane group 0..3 -> sites 2g,2g+1
    const int fl = lane & 15;               // filter-in-tile / frag row-col
    const float* lp  = conv + (size_t)blockIdx.x * 24576 + (2 * g) * 384 + fl * 3;
    const float* lpA = lp + wave * 96;      // A-tiles 2w,2w+1 (addr runtime: OK)

    f32x4 acc0[8], acc1[8];
#pragma unroll
    for (int cc = 0; cc < 8; ++cc) { acc0[cc] = (f32x4)0.f; acc1[cc] = (f32x4)0.f; }

    OctB O0, O1;
    load_oct(lp,        lpA,        O0);    // octet 0
    load_oct(lp + 3072, lpA + 3072, O1);    // octet 1

#pragma unroll
    for (int oo = 0; oo < 8; oo += 2) {
        consume_oct(O0, acc0, acc1);        // waits only O0's loads (FIFO)
        if (oo + 2 < 8) load_oct(lp + (oo + 2) * 3072, lpA + (oo + 2) * 3072, O0);
        consume_oct(O1, acc0, acc1);
        if (oo + 3 < 8) load_oct(lp + (oo + 3) * 3072, lpA + (oo + 3) * 3072, O1);
    }

    // epilogue: bf16-pair-packed partial tile (round-7 validated layout):
    // u32[pr*128+col] = pack(G[r0], G[r0+16]), pr = wave*16 + rsub + j,
    // r0 = wave*32 + rsub + j, col = cc*16 + fl.
    unsigned int* myp = pp + (size_t)blockIdx.x * NPAIRQ;
    const int rsub = (lane >> 4) << 2;
#pragma unroll
    for (int cc = 0; cc < 8; ++cc) {
        const int col = cc * 16 + fl;
#pragma unroll
        for (int j = 0; j < 4; ++j) {
            const int pr = wave * 16 + rsub + j;
            myp[pr * FDIM + col] = pack_bf2(acc0[cc][j], acc1[cc][j]);
        }
    }
}

// ------------------------------------------------- partial reduce (bf16 pairs)
// 512 blocks x 256 thr: block owns 16 packed columns; 16 slices of 64 tiles.
__global__ void __launch_bounds__(256) reduce_kernel(
        const unsigned int* __restrict__ pp, float* __restrict__ gram) {
    __shared__ float red[16][16][2];
    const int tid = threadIdx.x;
    const int u = tid & 15;
    const int s = tid >> 4;                 // 0..15
    const int qq = blockIdx.x * 16 + u;
    float lo = 0.f, hi = 0.f;
#pragma unroll 8
    for (int b = s * 64; b < s * 64 + 64; ++b) {
        const unsigned int v = pp[(size_t)b * NPAIRQ + qq];
        lo += __uint_as_float(v << 16);
        hi += __uint_as_float(v & 0xffff0000u);
    }
    red[s][u][0] = lo; red[s][u][1] = hi;
    __syncthreads();
    if (tid < 32) {
        const int u2 = tid >> 1, h = tid & 1;
        float x = 0.f;
#pragma unroll
        for (int s2 = 0; s2 < 16; ++s2) x += red[s2][u2][h];
        gram[(blockIdx.x * 16 + u2) * 2 + h] = x;
    }
}

// ------------------------------------------------------------ finalize
// gram layout: g = (pr*128+col)*2 + h, row = (pr>>4)*32 + (pr&15) + 16h
__global__ void __launch_bounds__(256) finalize_kernel(
        const float* __restrict__ gram, const float* __restrict__ mse_part,
        float* __restrict__ out) {
    __shared__ float rn[FDIM];
    __shared__ float redS[4], redM[4];
    const int tid = threadIdx.x;
    if (tid < FDIM) {
        const int row = tid;
        const int pr = (row >> 5) * 16 + (row & 15);
        const int h = (row >> 4) & 1;
        rn[row] = rsqrtf(gram[(pr * FDIM + row) * 2 + h]);
    }
    __syncthreads();
    float s = 0.f;
    for (int i = tid; i < GRAM_ELEMS; i += 256) {
        const int h = i & 1;
        const int qq = i >> 1;
        const int col = qq & 127;
        const int pr = qq >> 7;
        const int row = (pr >> 4) * 32 + (pr & 15) + (h << 4);
        const float gv = gram[i] * rn[row] * rn[col];
        if (row != col && gv > TAU && gv <= 1.0f) s += gv;
    }
    float m = 0.f;
#pragma unroll 8
    for (int j = 0; j < 8; ++j) m += mse_part[tid * 8 + j];   // 2048 entries
    for (int off = 32; off; off >>= 1) {
        s += __shfl_down(s, off);
        m += __shfl_down(m, off);
    }
    if ((tid & 63) == 0) { redS[tid >> 6] = s; redM[tid >> 6] = m; }
    __syncthreads();
    if (tid == 0)
        out[0] = (redM[0] + redM[1] + redM[2] + redM[3]) * (1.0f / 8192000.0f) +
                 ALPHA * (redS[0] + redS[1] + redS[2] + redS[3]);
}

extern "C" void kernel_launch(void* const* d_in, const int* in_sizes, int n_in,
                              void* d_out, int out_size, void* d_ws, size_t ws_size,
                              hipStream_t stream) {
    const float* output = (const float*)d_in[0];
    const float* target = (const float*)d_in[1];
    const float* conv   = (const float*)d_in[2];
    float* out = (float*)d_out;

    float* wsf       = (float*)d_ws;
    float* mse_part  = wsf;                              // 2048 floats
    float* gram      = wsf + NMSE;                       // 16384 floats
    unsigned int* pp = (unsigned int*)(wsf + NMSE + GRAM_ELEMS); // 33.6 MB
    (void)ws_size;   // need ~33.7 MB; harness provides ~402 MB (r5 profile)

    // all buffers fully written before read -> no memsets
    fused_kernel<<<NGRAM + NMSE, 256, 0, stream>>>(output, target, conv,
                                                   mse_part, pp);
    reduce_kernel<<<NPAIRQ / 16, 256, 0, stream>>>(pp, gram);
    finalize_kernel<<<1, 256, 0, stream>>>(gram, mse_part, out);
}

// Round 10
// 57.770 us; speedup vs baseline: 1.2457x; 1.2457x over previous
//
#include <hip/hip_runtime.h>
#include <hip/hip_bf16.h>

// loss = mean((output-target)^2) + ALPHA * sum(masked cosine Gram of
// V[128][196608]), V[f][d] = conv_w[o][i][f][k], d=(site,k), site=(o,i).
//
// Round 10: zero-redundancy + max-TLP. Gram role: 512 blocks x 4 chunks of
// 32 sites; stage+convert fp32->bf16 tile in a SINGLE 26.6 KB LDS buffer
// (2 syncthreads/chunk); 16 MFMA x3 K-steps per wave. launch_bounds(256,4)
// -> <=128 VGPR -> 4 blocks/CU = 16 waves/CU; inter-block TLP (the proven
// mse recipe) hides latency and barrier bubbles. MSE co-runs as 1536 extra
// blocks of the same grid. conv is read exactly once (waves share via LDS).
// pp/reduce/finalize layouts are the round-6/7 validated ones.

typedef __attribute__((ext_vector_type(8))) short bf16x8;   // 8 bf16 = 4 VGPR
typedef __attribute__((ext_vector_type(4))) float f32x4;

#define ALPHA 0.0005f
#define TAU 0.2f

#define FDIM 128
#define TSTRIDE 52          // tile row stride in dwords (48 data + 4 pad)
#define GRAM_NBLK 512
#define NMSE 1536
#define CHUNK_F4 3072       // 32 sites * 96 float4
#define GRAM_ELEMS 16384
#define NPAIRQ 8192         // packed u32 per partial tile
#define MSE_N4 2048000      // 8192*1000/4

// branchless RNE f32->bf16 pair pack
__device__ __forceinline__ unsigned int pack_bf2(float lo, float hi) {
    union { float f; unsigned int u; } a, b;
    a.f = lo; b.f = hi;
    unsigned int al = (a.u + 0x7fffu + ((a.u >> 16) & 1u)) >> 16;
    unsigned int bh = (b.u + 0x7fffu + ((b.u >> 16) & 1u)) & 0xffff0000u;
    return (al & 0xffffu) | bh;
}

__device__ __forceinline__ void mfmaph(const unsigned short* __restrict__ tu,
                                       int wave, int colr, int hi8,
                                       f32x4 (&acc0)[8], f32x4 (&acc1)[8]) {
#pragma unroll
    for (int ks = 0; ks < 3; ++ks) {
        const int koff = ks * 32 + hi8;
        bf16x8 a0 = *reinterpret_cast<const bf16x8*>(
            &tu[(wave * 32 + colr) * (TSTRIDE * 2) + koff]);
        bf16x8 a1 = *reinterpret_cast<const bf16x8*>(
            &tu[(wave * 32 + 16 + colr) * (TSTRIDE * 2) + koff]);
#pragma unroll
        for (int cc = 0; cc < 8; ++cc) {
            bf16x8 b = *reinterpret_cast<const bf16x8*>(
                &tu[(cc * 16 + colr) * (TSTRIDE * 2) + koff]);
            acc0[cc] = __builtin_amdgcn_mfma_f32_16x16x32_bf16(a0, b, acc0[cc], 0, 0, 0);
            acc1[cc] = __builtin_amdgcn_mfma_f32_16x16x32_bf16(a1, b, acc1[cc], 0, 0, 0);
        }
    }
}

// --------------------------------------------- mixed-role fused kernel
// blocks [0, GRAM_NBLK): Gram tile partials. [GRAM_NBLK, +NMSE): MSE.
__global__ void __launch_bounds__(256, 4) fused_kernel(
        const float* __restrict__ o, const float* __restrict__ t,
        const float* __restrict__ conv,
        float* __restrict__ mse_part, unsigned int* __restrict__ pp) {
    __shared__ unsigned int tile[FDIM * TSTRIDE];   // 26624 B
    __shared__ float red[4];
    const int tid = threadIdx.x;
    const int lane = tid & 63;
    const int wave = tid >> 6;

    if (blockIdx.x >= GRAM_NBLK) {
        // ---------------- MSE role ----------------
        const int mb = blockIdx.x - GRAM_NBLK;
        const int gid = mb * 256 + tid;
        const f32x4* o4 = reinterpret_cast<const f32x4*>(o);
        const f32x4* t4 = reinterpret_cast<const f32x4*>(t);
        float s = 0.f;
        for (int i = gid; i < MSE_N4; i += NMSE * 256) {
            f32x4 a = o4[i], b = t4[i];
            f32x4 d = a - b;
            s += d[0]*d[0] + d[1]*d[1] + d[2]*d[2] + d[3]*d[3];
        }
        for (int off = 32; off; off >>= 1) s += __shfl_down(s, off);
        if (lane == 0) red[wave] = s;
        __syncthreads();
        if (tid == 0) mse_part[mb] = red[0] + red[1] + red[2] + red[3];
        return;
    }

    // ---------------- Gram role ----------------
    const int p = tid >> 4;                 // site pair 0..15
    const int q = tid & 15;                 // float4 sub-offset 0..15
    const int colr = lane & 15;
    const int hi8 = (lane >> 4) * 8;
    const unsigned short* tileu = reinterpret_cast<const unsigned short*>(tile);

    f32x4 acc0[8], acc1[8];
#pragma unroll
    for (int cc = 0; cc < 8; ++cc) { acc0[cc] = (f32x4)0.f; acc1[cc] = (f32x4)0.f; }

    const f32x4* src4 = reinterpret_cast<const f32x4*>(conv);
    const size_t cb = (size_t)blockIdx.x * (4 * CHUNK_F4) + (2 * p) * 96 + q;

    for (int c = 0; c < 4; ++c) {
        __syncthreads();                    // tile free (prev chunk's mfma done)
        // stage+convert: 6 x (2 f32x4 loads -> 4 packed b32 LDS writes).
        // minimal register footprint; TLP (16 waves/CU) hides load latency.
#pragma unroll
        for (int it = 0; it < 6; ++it) {
            const f32x4 v0 = src4[cb + c * CHUNK_F4 + 16 * it];
            const f32x4 v1 = src4[cb + c * CHUNK_F4 + 96 + 16 * it];
            const int off4 = q + 16 * it;
#pragma unroll
            for (int u = 0; u < 4; ++u) {
                const int idx = off4 * 4 + u;       // [0,384): f*3 + k
                const int f = idx / 3;              // magic-mul
                const int k = idx - 3 * f;
                tile[f * TSTRIDE + k * 16 + p] = pack_bf2(v0[u], v1[u]);
            }
        }
        __syncthreads();                    // tile ready
        mfmaph(tileu, wave, colr, hi8, acc0, acc1);
    }

    // epilogue: bf16-pair-packed partial tile (validated layout):
    // u32[pr*128+col] = pack(G[r0], G[r0+16]), pr = wave*16 + rsub + j,
    // r0 = wave*32 + rsub + j, col = cc*16 + colr.
    unsigned int* myp = pp + (size_t)blockIdx.x * NPAIRQ;
    const int rsub = (lane >> 4) << 2;
#pragma unroll
    for (int cc = 0; cc < 8; ++cc) {
        const int col = cc * 16 + colr;
#pragma unroll
        for (int j = 0; j < 4; ++j) {
            const int pr = wave * 16 + rsub + j;
            myp[pr * FDIM + col] = pack_bf2(acc0[cc][j], acc1[cc][j]);
        }
    }
}

// ------------------------------------------------- partial reduce (bf16 pairs)
// 512 blocks x 256 thr: block owns 16 packed columns; 16 slices of 32 tiles.
__global__ void __launch_bounds__(256) reduce_kernel(
        const unsigned int* __restrict__ pp, float* __restrict__ gram) {
    __shared__ float red[16][16][2];
    const int tid = threadIdx.x;
    const int u = tid & 15;
    const int s = tid >> 4;                 // 0..15
    const int qq = blockIdx.x * 16 + u;
    float lo = 0.f, hi = 0.f;
#pragma unroll 8
    for (int b = s * 32; b < s * 32 + 32; ++b) {
        const unsigned int v = pp[(size_t)b * NPAIRQ + qq];
        lo += __uint_as_float(v << 16);
        hi += __uint_as_float(v & 0xffff0000u);
    }
    red[s][u][0] = lo; red[s][u][1] = hi;
    __syncthreads();
    if (tid < 32) {
        const int u2 = tid >> 1, h = tid & 1;
        float x = 0.f;
#pragma unroll
        for (int s2 = 0; s2 < 16; ++s2) x += red[s2][u2][h];
        gram[(blockIdx.x * 16 + u2) * 2 + h] = x;
    }
}

// ------------------------------------------------------------ finalize
// gram layout: g = (pr*128+col)*2 + h, row = (pr>>4)*32 + (pr&15) + 16h
__global__ void __launch_bounds__(256) finalize_kernel(
        const float* __restrict__ gram, const float* __restrict__ mse_part,
        float* __restrict__ out) {
    __shared__ float rn[FDIM];
    __shared__ float redS[4], redM[4];
    const int tid = threadIdx.x;
    if (tid < FDIM) {
        const int row = tid;
        const int pr = (row >> 5) * 16 + (row & 15);
        const int h = (row >> 4) & 1;
        rn[row] = rsqrtf(gram[(pr * FDIM + row) * 2 + h]);
    }
    __syncthreads();
    float s = 0.f;
    for (int i = tid; i < GRAM_ELEMS; i += 256) {
        const int h = i & 1;
        const int qq = i >> 1;
        const int col = qq & 127;
        const int pr = qq >> 7;
        const int row = (pr >> 4) * 32 + (pr & 15) + (h << 4);
        const float gv = gram[i] * rn[row] * rn[col];
        if (row != col && gv > TAU && gv <= 1.0f) s += gv;
    }
    float m = 0.f;
#pragma unroll 6
    for (int j = 0; j < 6; ++j) m += mse_part[tid * 6 + j];   // 1536 entries
    for (int off = 32; off; off >>= 1) {
        s += __shfl_down(s, off);
        m += __shfl_down(m, off);
    }
    if ((tid & 63) == 0) { redS[tid >> 6] = s; redM[tid >> 6] = m; }
    __syncthreads();
    if (tid == 0)
        out[0] = (redM[0] + redM[1] + redM[2] + redM[3]) * (1.0f / 8192000.0f) +
                 ALPHA * (redS[0] + redS[1] + redS[2] + redS[3]);
}

extern "C" void kernel_launch(void* const* d_in, const int* in_sizes, int n_in,
                              void* d_out, int out_size, void* d_ws, size_t ws_size,
                              hipStream_t stream) {
    const float* output = (const float*)d_in[0];
    const float* target = (const float*)d_in[1];
    const float* conv   = (const float*)d_in[2];
    float* out = (float*)d_out;

    float* wsf       = (float*)d_ws;
    float* mse_part  = wsf;                              // 1536 floats
    float* gram      = wsf + NMSE;                       // 16384 floats
    unsigned int* pp = (unsigned int*)(wsf + NMSE + GRAM_ELEMS); // 16.8 MB
    (void)ws_size;   // need ~16.9 MB; harness provides ~402 MB (r5 profile)

    // all buffers fully written before read -> no memsets
    fused_kernel<<<GRAM_NBLK + NMSE, 256, 0, stream>>>(output, target, conv,
                                                       mse_part, pp);
    reduce_kernel<<<NPAIRQ / 16, 256, 0, stream>>>(pp, gram);
    finalize_kernel<<<1, 256, 0, stream>>>(gram, mse_part, out);
}